// Round 9
// baseline (252.629 us; speedup 1.0000x reference)
//
#include <hip/hip_runtime.h>
#include <cstdint>
#include <cstddef>

typedef __bf16 bf16;
typedef bf16 bf16x8 __attribute__((ext_vector_type(8)));
typedef float f32x4 __attribute__((ext_vector_type(4)));
typedef float f32x16 __attribute__((ext_vector_type(16)));

__device__ inline f32x4 mfma_16x16x32(bf16x8 a, bf16x8 b, f32x4 c) {
    return __builtin_amdgcn_mfma_f32_16x16x32_bf16(a, b, c, 0, 0, 0);
}
__device__ inline f32x16 mfma_32x32x16(bf16x8 a, bf16x8 b, f32x16 c) {
    return __builtin_amdgcn_mfma_f32_32x32x16_bf16(a, b, c, 0, 0, 0);
}
// v_cvt_pk_bf16_f32: no builtin on gfx950 (m240) — dst.lo = bf16(lo), dst.hi = bf16(hi)
__device__ inline uint32_t cvt_pk_bf16(float lo, float hi) {
    uint32_t r;
    asm("v_cvt_pk_bf16_f32 %0, %1, %2" : "=v"(r) : "v"(lo), "v"(hi));
    return r;
}

// async global->LDS, 16B per lane; LDS dst is wave-uniform base + lane*16
#define GLD16(gsrc, ldst)                                                              \
    __builtin_amdgcn_global_load_lds(                                                  \
        (const __attribute__((address_space(1))) uint32_t*)(gsrc),                     \
        (__attribute__((address_space(3))) uint32_t*)(ldst), 16, 0, 0)

// ---------------- fp32 -> bf16 convert (x + 4 weights, single launch) ----------------
__global__ void cvt_all(const float* __restrict__ x,
                        const float* __restrict__ w0, const float* __restrict__ w1,
                        const float* __restrict__ w2, const float* __restrict__ w3,
                        bf16* __restrict__ xb,
                        bf16* __restrict__ d0, bf16* __restrict__ d1,
                        bf16* __restrict__ d2, bf16* __restrict__ d3) {
    const int id = blockIdx.x;
    const float* src;
    bf16* dst;
    int boff;
    if (id < 8192) {
        src = x; dst = xb; boff = id;
    } else {
        const int r = id - 8192;
        const int z = r >> 10;
        boff = r & 1023;
        src = (z == 0) ? w0 : (z == 1) ? w1 : (z == 2) ? w2 : w3;
        dst = (z == 0) ? d0 : (z == 1) ? d1 : (z == 2) ? d2 : d3;
    }
    const size_t i = ((size_t)boff * 256 + threadIdx.x) * 4;
    float4 f = *(const float4*)(src + i);
    union { bf16 o4[4]; uint2 u; } pk;
    pk.o4[0] = (bf16)f.x; pk.o4[1] = (bf16)f.y; pk.o4[2] = (bf16)f.z; pk.o4[3] = (bf16)f.w;
    *(uint2*)(dst + i) = pk.u;
}

#define QSCALE 0.18033688011112042f   // (1/8) * log2(e)

// ---------------- gemm_qkv: m201-faithful 256x256 / 8-wave / 8-phase ----------------
// R16: launch_bounds (512,2) -> (512,1). R15's MfmaUtil-27% regression was the
// 128-VGPR allocator cap ((512,2) = min 2 waves/EU): acc alone is 128 f32, so
// the compiler thrashed v_accvgpr moves. (512,1) lets V+A reach the 256/wave
// block-residency limit (8 waves x 256 = 2048-reg pool): acc -> 128 AGPRs,
// frags+addressing -> VGPRs. Schedule itself refcheck'd OK in R15.
//
// 4 phases per K-tile, EACH = {ds_read subtile || stage -> barrier ->
// lgkmcnt(0)+sched_barrier -> setprio1 -> 16 MFMA -> setprio0 -> barrier}.
// Region discipline: A regions fully read by p1-end (a0 HELD in regs through
// p3), B by p2-end. Distance-2 staging: p2 stages A(t+2), p3 stages B(t+2).
// vmcnt(8) ONCE per K-tile at p3-end; NEVER vmcnt(0) in steady state (m218).
// Tail: t=14 vmcnt(0), t=15 no wait. LDS 128 KiB dynamic, 1 block/CU, 8 waves.
// XOR-chunk swizzle retained. Grid 384 = 1.5 rounds (quantization tax ~25%).
__global__ __launch_bounds__(512, 1)
void gemm_qkv(const bf16* __restrict__ xb,
              const bf16* __restrict__ wq, const bf16* __restrict__ wk, const bf16* __restrict__ wv,
              bf16* __restrict__ qo, bf16* __restrict__ ko, bf16* __restrict__ vo)
{
    extern __shared__ char smem[];
    bf16 (*sA)[256][64] = (bf16 (*)[256][64])smem;                       // 2 x 32 KB
    bf16 (*sB)[256][64] = (bf16 (*)[256][64])(smem + 2 * 256 * 64 * 2);  // 2 x 32 KB
    const int tid = threadIdx.x;
    const int lane = tid & 63, wave = tid >> 6;        // 8 waves
    const int wm = wave >> 2, wn = wave & 3;           // 2M x 4N -> wave out 128x64
    const int quad = lane >> 4, ln = lane & 15;
    const int lr = lane >> 3;
    const int ssc = ((lane & 7) ^ lr) * 8;             // swizzled staging source col
    const int lnm = ln & 7;
    const int rc0 = (quad ^ lnm) * 8;
    const int rc1 = ((4 | quad) ^ lnm) * 8;
    const int id = blockIdx.x;
    const int z = id >> 7;                 // 0..2
    const int xt = (id & 127) >> 5;        // 0..3  col tile (256 wide)
    const int yt = id & 31;                // 0..31 row tile (XCD = yt%8)
    const bf16* W = (z == 0) ? wq : (z == 1) ? wk : wv;
    const int row0 = yt * 256;
    const int col0 = xt * 256;
    const int srow = tid >> 3;                         // 0..63 staging row in group
    const int ldsr = wave * 8;                         // wave-uniform LDS base row
    const bf16* aS = xb + (size_t)(row0 + srow) * 1024 + ssc;
    const bf16* bS = W  + (size_t)(col0 + srow) * 1024 + ssc;

    f32x4 acc[8][4];
    const f32x4 zero = {0.f, 0.f, 0.f, 0.f};
#pragma unroll
    for (int i = 0; i < 8; ++i)
#pragma unroll
        for (int j = 0; j < 4; ++j) acc[i][j] = zero;

    // stage A / B of tile tn (4 GLD16 each; 64-row groups)
#define STA(tn) do { const int cb_ = (tn) & 1; const size_t ko_ = (size_t)(tn) * 64;  \
    GLD16(aS +            ko_, &sA[cb_][      ldsr][0]);                              \
    GLD16(aS +  64*1024 + ko_, &sA[cb_][ 64 + ldsr][0]);                              \
    GLD16(aS + 128*1024 + ko_, &sA[cb_][128 + ldsr][0]);                              \
    GLD16(aS + 192*1024 + ko_, &sA[cb_][192 + ldsr][0]); } while (0)
#define STB(tn) do { const int cb_ = (tn) & 1; const size_t ko_ = (size_t)(tn) * 64;  \
    GLD16(bS +            ko_, &sB[cb_][      ldsr][0]);                              \
    GLD16(bS +  64*1024 + ko_, &sB[cb_][ 64 + ldsr][0]);                              \
    GLD16(bS + 128*1024 + ko_, &sB[cb_][128 + ldsr][0]);                              \
    GLD16(bS + 192*1024 + ko_, &sB[cb_][192 + ldsr][0]); } while (0)

#define LGKM0_FENCE                                                           \
    asm volatile("s_waitcnt lgkmcnt(0)" ::: "memory");                        \
    __builtin_amdgcn_sched_barrier(0);

#define QITER(T, DOSTAGE, EVM) do {                                           \
    const int cur_ = (T) & 1;                                                 \
    bf16x8 a0_[4][2], a1_[4][2], b0_[2][2], b1_[2][2];                        \
    /* -- p0 (mh0 x nh0): 12 ds_read -- */                                    \
    _Pragma("unroll")                                                         \
    for (int mi = 0; mi < 4; ++mi) {                                          \
        a0_[mi][0] = *(const bf16x8*)(&sA[cur_][wm * 128 + mi * 16 + ln][rc0]); \
        a0_[mi][1] = *(const bf16x8*)(&sA[cur_][wm * 128 + mi * 16 + ln][rc1]); \
    }                                                                         \
    _Pragma("unroll")                                                         \
    for (int ni = 0; ni < 2; ++ni) {                                          \
        b0_[ni][0] = *(const bf16x8*)(&sB[cur_][wn * 64 + ni * 16 + ln][rc0]); \
        b0_[ni][1] = *(const bf16x8*)(&sB[cur_][wn * 64 + ni * 16 + ln][rc1]); \
    }                                                                         \
    __builtin_amdgcn_s_barrier();                                             \
    LGKM0_FENCE                                                               \
    __builtin_amdgcn_s_setprio(1);                                            \
    _Pragma("unroll")                                                         \
    for (int mi = 0; mi < 4; ++mi)                                            \
        _Pragma("unroll")                                                     \
        for (int ni = 0; ni < 2; ++ni) {                                      \
            acc[mi][ni] = mfma_16x16x32(a0_[mi][0], b0_[ni][0], acc[mi][ni]); \
            acc[mi][ni] = mfma_16x16x32(a0_[mi][1], b0_[ni][1], acc[mi][ni]); \
        }                                                                     \
    __builtin_amdgcn_s_setprio(0);                                            \
    __builtin_amdgcn_s_barrier();                                             \
    /* -- p1 (mh1 x nh0): 8 ds_read -- */                                     \
    _Pragma("unroll")                                                         \
    for (int mi = 0; mi < 4; ++mi) {                                          \
        a1_[mi][0] = *(const bf16x8*)(&sA[cur_][wm * 128 + 64 + mi * 16 + ln][rc0]); \
        a1_[mi][1] = *(const bf16x8*)(&sA[cur_][wm * 128 + 64 + mi * 16 + ln][rc1]); \
    }                                                                         \
    __builtin_amdgcn_s_barrier();                                             \
    LGKM0_FENCE                                                               \
    __builtin_amdgcn_s_setprio(1);                                            \
    _Pragma("unroll")                                                         \
    for (int mi = 0; mi < 4; ++mi)                                            \
        _Pragma("unroll")                                                     \
        for (int ni = 0; ni < 2; ++ni) {                                      \
            acc[4 + mi][ni] = mfma_16x16x32(a1_[mi][0], b0_[ni][0], acc[4 + mi][ni]); \
            acc[4 + mi][ni] = mfma_16x16x32(a1_[mi][1], b0_[ni][1], acc[4 + mi][ni]); \
        }                                                                     \
    __builtin_amdgcn_s_setprio(0);                                            \
    __builtin_amdgcn_s_barrier();                                             \
    /* -- p2 (mh1 x nh1): 4 ds_read + stage A(t+2) (A free after p1-end) -- */ \
    _Pragma("unroll")                                                         \
    for (int ni = 0; ni < 2; ++ni) {                                          \
        b1_[ni][0] = *(const bf16x8*)(&sB[cur_][wn * 64 + 32 + ni * 16 + ln][rc0]); \
        b1_[ni][1] = *(const bf16x8*)(&sB[cur_][wn * 64 + 32 + ni * 16 + ln][rc1]); \
    }                                                                         \
    if (DOSTAGE) { STA((T) + 2); }                                            \
    __builtin_amdgcn_s_barrier();                                             \
    LGKM0_FENCE                                                               \
    __builtin_amdgcn_s_setprio(1);                                            \
    _Pragma("unroll")                                                         \
    for (int mi = 0; mi < 4; ++mi)                                            \
        _Pragma("unroll")                                                     \
        for (int ni = 0; ni < 2; ++ni) {                                      \
            acc[4 + mi][2 + ni] = mfma_16x16x32(a1_[mi][0], b1_[ni][0], acc[4 + mi][2 + ni]); \
            acc[4 + mi][2 + ni] = mfma_16x16x32(a1_[mi][1], b1_[ni][1], acc[4 + mi][2 + ni]); \
        }                                                                     \
    __builtin_amdgcn_s_setprio(0);                                            \
    __builtin_amdgcn_s_barrier();                                             \
    /* -- p3 (mh0 x nh1): regs only (a0 held); stage B(t+2) (B free p2-end) -- */ \
    if (DOSTAGE) { STB((T) + 2); }                                            \
    __builtin_amdgcn_s_barrier();                                             \
    __builtin_amdgcn_s_setprio(1);                                            \
    _Pragma("unroll")                                                         \
    for (int mi = 0; mi < 4; ++mi)                                            \
        _Pragma("unroll")                                                     \
        for (int ni = 0; ni < 2; ++ni) {                                      \
            acc[mi][2 + ni] = mfma_16x16x32(a0_[mi][0], b1_[ni][0], acc[mi][2 + ni]); \
            acc[mi][2 + ni] = mfma_16x16x32(a0_[mi][1], b1_[ni][1], acc[mi][2 + ni]); \
        }                                                                     \
    __builtin_amdgcn_s_setprio(0);                                            \
    if ((EVM) == 8)      asm volatile("s_waitcnt vmcnt(8)" ::: "memory");     \
    else if ((EVM) == 0) asm volatile("s_waitcnt vmcnt(0)" ::: "memory");     \
    __builtin_amdgcn_s_barrier();                                             \
} while (0)

    // prologue: tiles 0 and 1 in flight; tile0 guaranteed landed
    STA(0); STB(0); STA(1); STB(1);
    asm volatile("s_waitcnt vmcnt(8)" ::: "memory");
    __builtin_amdgcn_s_barrier();
#pragma unroll 2
    for (int t = 0; t < 14; ++t) { QITER(t, 1, 8); }
    QITER(14, 0, 0);
    QITER(15, 0, -1);

    // ---- epilogue ----
    if (z == 2) {
#pragma unroll
        for (int i = 0; i < 8; ++i)
#pragma unroll
            for (int j = 0; j < 4; ++j) {
                int gm0 = row0 + wm * 128 + (i >> 2) * 64 + (i & 3) * 16 + quad * 4;
                int gn = col0 + wn * 64 + (j >> 1) * 32 + (j & 1) * 16 + ln;
                int b = gm0 >> 11, t = gm0 & 2047;
                int h = gn >> 6,  d = gn & 63;
                union { bf16 v[4]; uint2 u; } pk;
#pragma unroll
                for (int e = 0; e < 4; ++e) pk.v[e] = (bf16)acc[i][j][e];
                *(uint2*)(&vo[((size_t)((b * 16 + h) * 64 + d)) * 2048 + t]) = pk.u;
            }
    } else {
        const float scale = (z == 0) ? QSCALE : 1.0f;
        bf16* outp = (z == 0) ? qo : ko;
#pragma unroll
        for (int i = 0; i < 8; ++i)
#pragma unroll
            for (int j = 0; j < 4; ++j)
#pragma unroll
                for (int e = 0; e < 4; ++e) {
                    int gm = row0 + wm * 128 + (i >> 2) * 64 + (i & 3) * 16 + quad * 4 + e;
                    int gn = col0 + wn * 64 + (j >> 1) * 32 + (j & 1) * 16 + ln;
                    int b = gm >> 11, t = gm & 2047;
                    int h = gn >> 6,  d = gn & 63;
                    outp[((size_t)((b * 16 + h) * 2048 + t)) * 64 + d] = (bf16)(acc[i][j][e] * scale);
                }
    }
#undef STA
#undef STB
#undef QITER
}

// ---------------- gemm_out: m97 128x128 (unchanged — 256^2 grid would be 0.5 rounds) ----------------
#define BM 128
#define BN 128
#define BK 64
__global__ __launch_bounds__(256, 2)
void gemm_out(const bf16* __restrict__ ab, const bf16* __restrict__ wo,
              const float* __restrict__ bias, float* __restrict__ out)
{
    __shared__ bf16 sA[BM][BK];
    __shared__ bf16 sB[BN][BK];
    const int K = 1024;
    const int tid = threadIdx.x;
    const int lane = tid & 63, wave = tid >> 6;
    const int wm = wave >> 1, wn = wave & 1;
    const int quad = lane >> 4, ln = lane & 15;
    const int lr = lane >> 3;
    const int ssc = ((lane & 7) ^ lr) * 8;
    const int lnm = ln & 7;
    const int rc0 = (quad ^ lnm) * 8;
    const int rc1 = ((4 | quad) ^ lnm) * 8;
    const int id = blockIdx.x;
    const int xt = id >> 6, yt = id & 63;
    const int row0 = yt * BM;
    const int col0 = xt * BN;

    f32x4 acc[4][4];
    const f32x4 zero = {0.f, 0.f, 0.f, 0.f};
#pragma unroll
    for (int i = 0; i < 4; ++i)
#pragma unroll
        for (int j = 0; j < 4; ++j) acc[i][j] = zero;

    for (int k0 = 0; k0 < K; k0 += BK) {
#pragma unroll
        for (int s = 0; s < 4; ++s) {
            int ra = wave * 32 + s * 8;
            GLD16(&ab[(size_t)(row0 + ra + lr) * K + k0 + ssc], &sA[ra][0]);
            GLD16(&wo[(size_t)(col0 + ra + lr) * K + k0 + ssc], &sB[ra][0]);
        }
        __syncthreads();
#pragma unroll
        for (int kk = 0; kk < BK; kk += 32) {
            const int rc = kk ? rc1 : rc0;
            bf16x8 af[4], bfv[4];
#pragma unroll
            for (int i = 0; i < 4; ++i) {
                af[i]  = *(const bf16x8*)(&sA[wm * 64 + i * 16 + ln][rc]);
                bfv[i] = *(const bf16x8*)(&sB[wn * 64 + i * 16 + ln][rc]);
            }
#pragma unroll
            for (int mi = 0; mi < 4; ++mi)
#pragma unroll
                for (int ni = 0; ni < 4; ++ni)
                    acc[mi][ni] = mfma_16x16x32(af[mi], bfv[ni], acc[mi][ni]);
        }
        __syncthreads();
    }
#pragma unroll
    for (int mi = 0; mi < 4; ++mi)
#pragma unroll
        for (int ni = 0; ni < 4; ++ni)
#pragma unroll
            for (int i = 0; i < 4; ++i) {
                int gm = row0 + wm * 64 + mi * 16 + quad * 4 + i;
                int gn = col0 + wn * 64 + ni * 16 + ln;
                out[(size_t)gm * 1024 + gn] = acc[mi][ni][i] + bias[gn];
            }
}

// ---------------- flash attention (causal) — R8/R14 structure, frozen ----------------
// See R14 notes: six structural variants (dbuf, balance, ILP-split, pairing)
// all measured within total-noise; this is the reference version.
__global__ __launch_bounds__(256, 2)
void flash_attn(const bf16* __restrict__ q, const bf16* __restrict__ k,
                const bf16* __restrict__ vt, bf16* __restrict__ ao)
{
    __shared__ bf16 sK[64][72];   // K rows x d
    __shared__ bf16 sV[64][72];   // V^T: d rows x k_local
    const int tid = threadIdx.x, lane = tid & 63, w = tid >> 6;
    const int c31 = lane & 31, hi = lane >> 5, hi8 = hi * 8;
    const int id = blockIdx.x;
    const int bh = id & 63;
    const int q0 = (15 - (id >> 6)) * 128;           // heavy blocks dispatch first
    const size_t base = (size_t)bh * (2048 * 64);
    const int sr = tid >> 3, sc = (tid & 7) * 8;
    const int rw = q0 + w * 32;                      // wave's first q-row
    const int rw31 = rw + 31;
    const int qrow = rw + c31;                       // this lane's q-row (S^T col)

    bf16x8 qf[4];
#pragma unroll
    for (int dt = 0; dt < 4; ++dt)
        qf[dt] = *(const bf16x8*)(&q[base + (size_t)qrow * 64 + dt * 16 + hi8]);

    const f32x16 z16 = {0.f,0.f,0.f,0.f,0.f,0.f,0.f,0.f,0.f,0.f,0.f,0.f,0.f,0.f,0.f,0.f};
    f32x16 o0 = z16, o1 = z16;     // O^T accum: d 0..31 / 32..63; col = q (lane-local)
    float lsum = 0.f;

    const int kend = q0 + 128;
    uint4 rKa = *(const uint4*)(&k [base + (size_t)sr * 64 + sc]);
    uint4 rKb = *(const uint4*)(&k [base + (size_t)(sr + 32) * 64 + sc]);
    uint4 rVa = *(const uint4*)(&vt[base + (size_t)sr * 2048 + sc]);
    uint4 rVb = *(const uint4*)(&vt[base + (size_t)(sr + 32) * 2048 + sc]);

    for (int k0 = 0; k0 < kend; k0 += 64) {
        __syncthreads();                 // prev tile's LDS readers done
        *(uint4*)(&sK[sr][sc])      = rKa;
        *(uint4*)(&sK[sr + 32][sc]) = rKb;
        *(uint4*)(&sV[sr][sc])      = rVa;
        *(uint4*)(&sV[sr + 32][sc]) = rVb;
        __syncthreads();
        if (k0 + 64 < kend) {            // prefetch next tile during compute
            int kn = k0 + 64;
            rKa = *(const uint4*)(&k [base + (size_t)(kn + sr) * 64 + sc]);
            rKb = *(const uint4*)(&k [base + (size_t)(kn + sr + 32) * 64 + sc]);
            rVa = *(const uint4*)(&vt[base + (size_t)sr * 2048 + kn + sc]);
            rVb = *(const uint4*)(&vt[base + (size_t)(sr + 32) * 2048 + kn + sc]);
        }
        if (k0 <= rw31) {                // tile intersects this wave's rows
#pragma unroll
            for (int kt = 0; kt < 2; ++kt) {
                const int ktb = k0 + kt * 32;
                if (ktb <= rw31) {       // 32-k subtile not fully above diagonal
                    bf16x8 kf0 = *(const bf16x8*)(&sK[kt * 32 + c31][ 0 + hi8]);
                    bf16x8 kf1 = *(const bf16x8*)(&sK[kt * 32 + c31][16 + hi8]);
                    bf16x8 kf2 = *(const bf16x8*)(&sK[kt * 32 + c31][32 + hi8]);
                    bf16x8 kf3 = *(const bf16x8*)(&sK[kt * 32 + c31][48 + hi8]);
                    f32x16 st = z16;
                    st = mfma_32x32x16(kf0, qf[0], st);
                    st = mfma_32x32x16(kf1, qf[1], st);
                    st = mfma_32x32x16(kf2, qf[2], st);
                    st = mfma_32x32x16(kf3, qf[3], st);
                    const int kb2 = ktb + hi * 4;
                    if (ktb + 31 > rw) {
#pragma unroll
                        for (int r = 0; r < 16; ++r) {
                            int kk = kb2 + (r & 3) + 8 * (r >> 2);
                            if (kk > qrow) st[r] = -INFINITY;
                        }
                    }
                    float pp[16];
                    float ps = 0.f;
#pragma unroll
                    for (int r = 0; r < 16; ++r) {
                        float p = __builtin_amdgcn_exp2f(st[r]);
                        ps += p;
                        pp[r] = p;
                    }
                    lsum += ps;
#pragma unroll
                    for (int ks = 0; ks < 2; ++ks) {
                        const int ob = ks * 8;
                        uint32_t a0 = cvt_pk_bf16(pp[ob + 0], pp[ob + 1]);
                        uint32_t a1 = cvt_pk_bf16(pp[ob + 2], pp[ob + 3]);
                        uint32_t a2 = cvt_pk_bf16(pp[ob + 4], pp[ob + 5]);
                        uint32_t a3 = cvt_pk_bf16(pp[ob + 6], pp[ob + 7]);
                        auto r02 = __builtin_amdgcn_permlane32_swap(a0, a2, false, false);
                        auto r13 = __builtin_amdgcn_permlane32_swap(a1, a3, false, false);
                        union { uint32_t u[4]; bf16x8 v; } af;
                        af.u[0] = r02[0]; af.u[1] = r13[0];
                        af.u[2] = r02[1]; af.u[3] = r13[1];
                        const int co = kt * 32 + ks * 16 + hi8;
                        bf16x8 v0 = *(const bf16x8*)(&sV[c31][co]);
                        bf16x8 v1 = *(const bf16x8*)(&sV[32 + c31][co]);
                        o0 = mfma_32x32x16(v0, af.v, o0);
                        o1 = mfma_32x32x16(v1, af.v, o1);
                    }
                }
            }
        }
    }

    float l = lsum + __shfl_xor(lsum, 32);
    const float inv = 1.0f / l;
    const int b = bh >> 4, h = bh & 15;
    bf16* orow = &ao[(size_t)(b * 2048 + qrow) * 1024 + h * 64];
#pragma unroll
    for (int g = 0; g < 4; ++g) {
        union { bf16 v4[4]; uint2 u; } pk0, pk1;
#pragma unroll
        for (int i = 0; i < 4; ++i) {
            pk0.v4[i] = (bf16)(o0[g * 4 + i] * inv);
            pk1.v4[i] = (bf16)(o1[g * 4 + i] * inv);
        }
        *(uint2*)(&orow[     g * 8 + hi * 4]) = pk0.u;
        *(uint2*)(&orow[32 + g * 8 + hi * 4]) = pk1.u;
    }
}

// ---------------- launch ----------------
extern "C" void kernel_launch(void* const* d_in, const int* in_sizes, int n_in,
                              void* d_out, int out_size, void* d_ws, size_t ws_size,
                              hipStream_t stream) {
    const float* x  = (const float*)d_in[0];
    // d_in[1] = mask (causal tril — analytic), d_in[7] = start_pos (==0)
    const float* Wq = (const float*)d_in[2];
    const float* Wk = (const float*)d_in[3];
    const float* Wv = (const float*)d_in[4];
    const float* Wo = (const float*)d_in[5];
    const float* bo = (const float*)d_in[6];
    float* out = (float*)d_out;

    char* p = (char*)d_ws;
    const size_t MK = 8192ull * 1024;
    bf16* xb  = (bf16*)p; p += MK * 2;
    bf16* wqb = (bf16*)p; p += (1ull << 20) * 2;
    bf16* wkb = (bf16*)p; p += (1ull << 20) * 2;
    bf16* wvb = (bf16*)p; p += (1ull << 20) * 2;
    bf16* wob = (bf16*)p; p += (1ull << 20) * 2;
    bf16* qb  = (bf16*)p; p += MK * 2;   // [B,H,T,64], scaled by 0.125*log2e
    bf16* kb  = (bf16*)p; p += MK * 2;   // [B,H,T,64]
    bf16* vtb = (bf16*)p; p += MK * 2;   // [B,H,64,T]
    bf16* aob = (bf16*)p; p += MK * 2;   // [B,T,1024]

    // 128 KiB dynamic LDS opt-in (host-side attribute set; graph-capture safe)
    static bool attr_done = false;
    if (!attr_done) {
        hipFuncSetAttribute(reinterpret_cast<const void*>(&gemm_qkv),
                            hipFuncAttributeMaxDynamicSharedMemorySize, 131072);
        attr_done = true;
    }

    cvt_all<<<12288, 256, 0, stream>>>(x, Wq, Wk, Wv, Wo, xb, wqb, wkb, wvb, wob);

    gemm_qkv<<<384, 512, 131072, stream>>>(xb, wqb, wkb, wvb, qb, kb, vtb);
    flash_attn<<<1024, 256, 0, stream>>>(qb, kb, vtb, aob);
    gemm_out<<<512, 256, 0, stream>>>(aob, wob, bo, out);
}

// Round 10
// 225.058 us; speedup vs baseline: 1.1225x; 1.1225x over previous
//
#include <hip/hip_runtime.h>
#include <cstdint>
#include <cstddef>

typedef __bf16 bf16;
typedef bf16 bf16x8 __attribute__((ext_vector_type(8)));
typedef float f32x4 __attribute__((ext_vector_type(4)));
typedef float f32x16 __attribute__((ext_vector_type(16)));

__device__ inline f32x4 mfma_16x16x32(bf16x8 a, bf16x8 b, f32x4 c) {
    return __builtin_amdgcn_mfma_f32_16x16x32_bf16(a, b, c, 0, 0, 0);
}
__device__ inline f32x16 mfma_32x32x16(bf16x8 a, bf16x8 b, f32x16 c) {
    return __builtin_amdgcn_mfma_f32_32x32x16_bf16(a, b, c, 0, 0, 0);
}
// v_cvt_pk_bf16_f32: no builtin on gfx950 (m240) — dst.lo = bf16(lo), dst.hi = bf16(hi)
__device__ inline uint32_t cvt_pk_bf16(float lo, float hi) {
    uint32_t r;
    asm("v_cvt_pk_bf16_f32 %0, %1, %2" : "=v"(r) : "v"(lo), "v"(hi));
    return r;
}

// async global->LDS, 16B per lane; LDS dst is wave-uniform base + lane*16
#define GLD16(gsrc, ldst)                                                              \
    __builtin_amdgcn_global_load_lds(                                                  \
        (const __attribute__((address_space(1))) uint32_t*)(gsrc),                     \
        (__attribute__((address_space(3))) uint32_t*)(ldst), 16, 0, 0)

// ---------------- fp32 -> bf16 convert (x + 4 weights, single launch) ----------------
// blocks 0..8191: x (8M elems); blocks 8192..12287: weights (4 x 1M elems)
// Memory-bound: ~72 MB total traffic ~= 11-12 us at ~6 TB/s (BW roofline).
__global__ void cvt_all(const float* __restrict__ x,
                        const float* __restrict__ w0, const float* __restrict__ w1,
                        const float* __restrict__ w2, const float* __restrict__ w3,
                        bf16* __restrict__ xb,
                        bf16* __restrict__ d0, bf16* __restrict__ d1,
                        bf16* __restrict__ d2, bf16* __restrict__ d3) {
    const int id = blockIdx.x;
    const float* src;
    bf16* dst;
    int boff;
    if (id < 8192) {
        src = x; dst = xb; boff = id;
    } else {
        const int r = id - 8192;
        const int z = r >> 10;
        boff = r & 1023;
        src = (z == 0) ? w0 : (z == 1) ? w1 : (z == 2) ? w2 : w3;
        dst = (z == 0) ? d0 : (z == 1) ? d1 : (z == 2) ? d2 : d3;
    }
    const size_t i = ((size_t)boff * 256 + threadIdx.x) * 4;
    float4 f = *(const float4*)(src + i);
    union { bf16 o4[4]; uint2 u; } pk;
    pk.o4[0] = (bf16)f.x; pk.o4[1] = (bf16)f.y; pk.o4[2] = (bf16)f.z; pk.o4[3] = (bf16)f.w;
    *(uint2*)(dst + i) = pk.u;
}

// ---------------- GEMM: y = x @ W^T, NT layout, m97-style async staging ----------------
// FINAL STRUCTURE for this shape: 128x128/BK64/2-barrier (measured 937-954 TF,
// MfmaUtil 38-40%, conflicts 0; grid 1536 = 3 EXACT rounds at 2 blocks/CU).
// Both 8-phase ports failed with identified causes:
//   R9  (256x128, 8 MFMA/phase):   68.8 us — phase granularity too fine.
//   R15/R16 (m201 256x256 16/ph): 72-73 us — 1 block/CU kills inter-block
//     overlap (m114 mechanism) + 384 blocks = 1.5-round grid quantization.
// On this shape the 2-barrier structure IS the local optimum; its ~950 TF is
// the known ceiling of the structure (m97 ladder).
//
// LDS XOR-chunk swizzle: rows are 128 B = exactly 32 banks; we store
// sX[r][c_chunk] = X[r][c_chunk ^ (r&7)] (16 B chunks) by XOR-ing the STAGING
// GLOBAL column with lane>>3 — LDS destinations stay lane-contiguous
// (global_load_lds requirement). Readers XOR their chunk with ln&7.
#define BM 128
#define BN 128
#define BK 64
#define QSCALE 0.18033688011112042f   // (1/8) * log2(e)

// 1D grid, id = z*512 + xt*64 + yt -> XCD = id%8 = yt%8: all 8 column-blocks
// sharing an A-tile land on ONE XCD; per-XCD set 8 A-tiles + W = 4 MB = L2.
// z=0: Q -> [B,H,T,64] (scaled); z=1: K -> [B,H,T,64]; z=2: V -> transposed [B,H,64,T]
__global__ __launch_bounds__(256, 2)
void gemm_qkv(const bf16* __restrict__ xb,
              const bf16* __restrict__ wq, const bf16* __restrict__ wk, const bf16* __restrict__ wv,
              bf16* __restrict__ qo, bf16* __restrict__ ko, bf16* __restrict__ vo)
{
    __shared__ bf16 sA[BM][BK];
    __shared__ bf16 sB[BN][BK];
    const int K = 1024;
    const int tid = threadIdx.x;
    const int lane = tid & 63, wave = tid >> 6;
    const int wm = wave >> 1, wn = wave & 1;
    const int quad = lane >> 4, ln = lane & 15;
    const int lr = lane >> 3;
    const int ssc = ((lane & 7) ^ lr) * 8;            // swizzled staging source col
    const int lnm = ln & 7;
    const int rc0 = (quad ^ lnm) * 8;                 // kk=0 read chunk offset
    const int rc1 = ((4 | quad) ^ lnm) * 8;           // kk=32 read chunk offset
    const int id = blockIdx.x;
    const int z = id >> 9;                 // 0..2
    const int xt = (id & 511) >> 6;        // 0..7   col tile
    const int yt = id & 63;                // 0..63  row tile (XCD = yt%8)
    const bf16* W = (z == 0) ? wq : (z == 1) ? wk : wv;
    const int row0 = yt * BM;
    const int col0 = xt * BN;

    f32x4 acc[4][4];
    const f32x4 zero = {0.f, 0.f, 0.f, 0.f};
#pragma unroll
    for (int i = 0; i < 4; ++i)
#pragma unroll
        for (int j = 0; j < 4; ++j) acc[i][j] = zero;

    for (int k0 = 0; k0 < K; k0 += BK) {
#pragma unroll
        for (int s = 0; s < 4; ++s) {
            int ra = wave * 32 + s * 8;
            GLD16(&xb[(size_t)(row0 + ra + lr) * K + k0 + ssc], &sA[ra][0]);
            GLD16(&W [(size_t)(col0 + ra + lr) * K + k0 + ssc], &sB[ra][0]);
        }
        __syncthreads();
#pragma unroll
        for (int kk = 0; kk < BK; kk += 32) {
            const int rc = kk ? rc1 : rc0;
            bf16x8 af[4], bfv[4];
#pragma unroll
            for (int i = 0; i < 4; ++i) {
                af[i]  = *(const bf16x8*)(&sA[wm * 64 + i * 16 + ln][rc]);
                bfv[i] = *(const bf16x8*)(&sB[wn * 64 + i * 16 + ln][rc]);
            }
#pragma unroll
            for (int mi = 0; mi < 4; ++mi)
#pragma unroll
                for (int ni = 0; ni < 4; ++ni)
                    acc[mi][ni] = mfma_16x16x32(af[mi], bfv[ni], acc[mi][ni]);
        }
        __syncthreads();
    }
    if (z == 2) {
#pragma unroll
        for (int mi = 0; mi < 4; ++mi)
#pragma unroll
            for (int ni = 0; ni < 4; ++ni) {
                int gm0 = row0 + wm * 64 + mi * 16 + quad * 4;
                int gn = col0 + wn * 64 + ni * 16 + ln;
                int b = gm0 >> 11, t = gm0 & 2047;
                int h = gn >> 6,  d = gn & 63;
                union { bf16 v[4]; uint2 u; } pk;
#pragma unroll
                for (int i = 0; i < 4; ++i) pk.v[i] = (bf16)acc[mi][ni][i];
                *(uint2*)(&vo[((size_t)((b * 16 + h) * 64 + d)) * 2048 + t]) = pk.u;
            }
    } else {
        const float scale = (z == 0) ? QSCALE : 1.0f;
        bf16* outp = (z == 0) ? qo : ko;
#pragma unroll
        for (int mi = 0; mi < 4; ++mi)
#pragma unroll
            for (int ni = 0; ni < 4; ++ni)
#pragma unroll
                for (int i = 0; i < 4; ++i) {
                    int gm = row0 + wm * 64 + mi * 16 + quad * 4 + i;
                    int gn = col0 + wn * 64 + ni * 16 + ln;
                    int b = gm >> 11, t = gm & 2047;
                    int h = gn >> 6,  d = gn & 63;
                    outp[((size_t)((b * 16 + h) * 2048 + t)) * 64 + d] = (bf16)(acc[mi][ni][i] * scale);
                }
    }
}

// Output projection: fp32 out + bias, row-major [M, N]. Same XCD swizzle and
// same LDS XOR-chunk swizzle.
__global__ __launch_bounds__(256, 2)
void gemm_out(const bf16* __restrict__ ab, const bf16* __restrict__ wo,
              const float* __restrict__ bias, float* __restrict__ out)
{
    __shared__ bf16 sA[BM][BK];
    __shared__ bf16 sB[BN][BK];
    const int K = 1024;
    const int tid = threadIdx.x;
    const int lane = tid & 63, wave = tid >> 6;
    const int wm = wave >> 1, wn = wave & 1;
    const int quad = lane >> 4, ln = lane & 15;
    const int lr = lane >> 3;
    const int ssc = ((lane & 7) ^ lr) * 8;
    const int lnm = ln & 7;
    const int rc0 = (quad ^ lnm) * 8;
    const int rc1 = ((4 | quad) ^ lnm) * 8;
    const int id = blockIdx.x;
    const int xt = id >> 6, yt = id & 63;
    const int row0 = yt * BM;
    const int col0 = xt * BN;

    f32x4 acc[4][4];
    const f32x4 zero = {0.f, 0.f, 0.f, 0.f};
#pragma unroll
    for (int i = 0; i < 4; ++i)
#pragma unroll
        for (int j = 0; j < 4; ++j) acc[i][j] = zero;

    for (int k0 = 0; k0 < K; k0 += BK) {
#pragma unroll
        for (int s = 0; s < 4; ++s) {
            int ra = wave * 32 + s * 8;
            GLD16(&ab[(size_t)(row0 + ra + lr) * K + k0 + ssc], &sA[ra][0]);
            GLD16(&wo[(size_t)(col0 + ra + lr) * K + k0 + ssc], &sB[ra][0]);
        }
        __syncthreads();
#pragma unroll
        for (int kk = 0; kk < BK; kk += 32) {
            const int rc = kk ? rc1 : rc0;
            bf16x8 af[4], bfv[4];
#pragma unroll
            for (int i = 0; i < 4; ++i) {
                af[i]  = *(const bf16x8*)(&sA[wm * 64 + i * 16 + ln][rc]);
                bfv[i] = *(const bf16x8*)(&sB[wn * 64 + i * 16 + ln][rc]);
            }
#pragma unroll
            for (int mi = 0; mi < 4; ++mi)
#pragma unroll
                for (int ni = 0; ni < 4; ++ni)
                    acc[mi][ni] = mfma_16x16x32(af[mi], bfv[ni], acc[mi][ni]);
        }
        __syncthreads();
    }
#pragma unroll
    for (int mi = 0; mi < 4; ++mi)
#pragma unroll
        for (int ni = 0; ni < 4; ++ni)
#pragma unroll
            for (int i = 0; i < 4; ++i) {
                int gm = row0 + wm * 64 + mi * 16 + quad * 4 + i;
                int gn = col0 + wn * 64 + ni * 16 + ln;
                out[(size_t)gm * 1024 + gn] = acc[mi][ni][i] + bias[gn];
            }
}

// ---------------- flash attention (causal) — R8/R14 structure, frozen ----------------
// q,k: [B,H,T,64] (q pre-scaled by 0.125*log2e); vt: [B,H,64,T].
// 1D grid: bh = id&63 -> XCD pin, heavy q-blocks first.
// Six structural variants (dbuf, slot-balance, ILP-split, strip-pairing, R8)
// all measured within total-noise (~54 us); this is the reference version.
//
// T12 structure: swapped-operand 32x32x16 MFMA, P fully in-register.
//  - S^T = mfma(A=Ktile, B=Q): scores lane-local (col=lane&31=q-row).
//  - mask+exp2 in regs; lsum ONE float/lane (+1 shfl_xor(32) at end).
//  - P->B-frag: 4x cvt_pk + 2x permlane32_swap per 16-k slice.
//  - PV swapped: O^T = mfma(A=V^T rows, B=P^T) -> q lane-local again ->
//    scalar inv, packed dwordx2 stores, no sP, no LDS transpose.
// __launch_bounds__(256,2): DO NOT raise to 4 (R3/R4/R5 scratch-spill).
__global__ __launch_bounds__(256, 2)
void flash_attn(const bf16* __restrict__ q, const bf16* __restrict__ k,
                const bf16* __restrict__ vt, bf16* __restrict__ ao)
{
    __shared__ bf16 sK[64][72];   // K rows x d
    __shared__ bf16 sV[64][72];   // V^T: d rows x k_local
    const int tid = threadIdx.x, lane = tid & 63, w = tid >> 6;
    const int c31 = lane & 31, hi = lane >> 5, hi8 = hi * 8;
    const int id = blockIdx.x;
    const int bh = id & 63;
    const int q0 = (15 - (id >> 6)) * 128;           // heavy blocks dispatch first
    const size_t base = (size_t)bh * (2048 * 64);
    const int sr = tid >> 3, sc = (tid & 7) * 8;
    const int rw = q0 + w * 32;                      // wave's first q-row
    const int rw31 = rw + 31;
    const int qrow = rw + c31;                       // this lane's q-row (S^T col)

    bf16x8 qf[4];
#pragma unroll
    for (int dt = 0; dt < 4; ++dt)
        qf[dt] = *(const bf16x8*)(&q[base + (size_t)qrow * 64 + dt * 16 + hi8]);

    const f32x16 z16 = {0.f,0.f,0.f,0.f,0.f,0.f,0.f,0.f,0.f,0.f,0.f,0.f,0.f,0.f,0.f,0.f};
    f32x16 o0 = z16, o1 = z16;     // O^T accum: d 0..31 / 32..63; col = q (lane-local)
    float lsum = 0.f;

    const int kend = q0 + 128;
    uint4 rKa = *(const uint4*)(&k [base + (size_t)sr * 64 + sc]);
    uint4 rKb = *(const uint4*)(&k [base + (size_t)(sr + 32) * 64 + sc]);
    uint4 rVa = *(const uint4*)(&vt[base + (size_t)sr * 2048 + sc]);
    uint4 rVb = *(const uint4*)(&vt[base + (size_t)(sr + 32) * 2048 + sc]);

    for (int k0 = 0; k0 < kend; k0 += 64) {
        __syncthreads();                 // prev tile's LDS readers done
        *(uint4*)(&sK[sr][sc])      = rKa;
        *(uint4*)(&sK[sr + 32][sc]) = rKb;
        *(uint4*)(&sV[sr][sc])      = rVa;
        *(uint4*)(&sV[sr + 32][sc]) = rVb;
        __syncthreads();
        if (k0 + 64 < kend) {            // prefetch next tile during compute
            int kn = k0 + 64;
            rKa = *(const uint4*)(&k [base + (size_t)(kn + sr) * 64 + sc]);
            rKb = *(const uint4*)(&k [base + (size_t)(kn + sr + 32) * 64 + sc]);
            rVa = *(const uint4*)(&vt[base + (size_t)sr * 2048 + kn + sc]);
            rVb = *(const uint4*)(&vt[base + (size_t)(sr + 32) * 2048 + kn + sc]);
        }
        if (k0 <= rw31) {                // tile intersects this wave's rows
#pragma unroll
            for (int kt = 0; kt < 2; ++kt) {
                const int ktb = k0 + kt * 32;
                if (ktb <= rw31) {       // 32-k subtile not fully above diagonal
                    bf16x8 kf0 = *(const bf16x8*)(&sK[kt * 32 + c31][ 0 + hi8]);
                    bf16x8 kf1 = *(const bf16x8*)(&sK[kt * 32 + c31][16 + hi8]);
                    bf16x8 kf2 = *(const bf16x8*)(&sK[kt * 32 + c31][32 + hi8]);
                    bf16x8 kf3 = *(const bf16x8*)(&sK[kt * 32 + c31][48 + hi8]);
                    f32x16 st = z16;
                    st = mfma_32x32x16(kf0, qf[0], st);
                    st = mfma_32x32x16(kf1, qf[1], st);
                    st = mfma_32x32x16(kf2, qf[2], st);
                    st = mfma_32x32x16(kf3, qf[3], st);
                    const int kb2 = ktb + hi * 4;
                    if (ktb + 31 > rw) {
#pragma unroll
                        for (int r = 0; r < 16; ++r) {
                            int kk = kb2 + (r & 3) + 8 * (r >> 2);
                            if (kk > qrow) st[r] = -INFINITY;
                        }
                    }
                    float pp[16];
                    float ps = 0.f;
#pragma unroll
                    for (int r = 0; r < 16; ++r) {
                        float p = __builtin_amdgcn_exp2f(st[r]);
                        ps += p;
                        pp[r] = p;
                    }
                    lsum += ps;
#pragma unroll
                    for (int ks = 0; ks < 2; ++ks) {
                        const int ob = ks * 8;
                        uint32_t a0 = cvt_pk_bf16(pp[ob + 0], pp[ob + 1]);
                        uint32_t a1 = cvt_pk_bf16(pp[ob + 2], pp[ob + 3]);
                        uint32_t a2 = cvt_pk_bf16(pp[ob + 4], pp[ob + 5]);
                        uint32_t a3 = cvt_pk_bf16(pp[ob + 6], pp[ob + 7]);
                        auto r02 = __builtin_amdgcn_permlane32_swap(a0, a2, false, false);
                        auto r13 = __builtin_amdgcn_permlane32_swap(a1, a3, false, false);
                        union { uint32_t u[4]; bf16x8 v; } af;
                        af.u[0] = r02[0]; af.u[1] = r13[0];
                        af.u[2] = r02[1]; af.u[3] = r13[1];
                        const int co = kt * 32 + ks * 16 + hi8;
                        bf16x8 v0 = *(const bf16x8*)(&sV[c31][co]);
                        bf16x8 v1 = *(const bf16x8*)(&sV[32 + c31][co]);
                        o0 = mfma_32x32x16(v0, af.v, o0);
                        o1 = mfma_32x32x16(v1, af.v, o1);
                    }
                }
            }
        }
    }

    float l = lsum + __shfl_xor(lsum, 32);
    const float inv = 1.0f / l;
    const int b = bh >> 4, h = bh & 15;
    bf16* orow = &ao[(size_t)(b * 2048 + qrow) * 1024 + h * 64];
#pragma unroll
    for (int g = 0; g < 4; ++g) {
        union { bf16 v4[4]; uint2 u; } pk0, pk1;
#pragma unroll
        for (int i = 0; i < 4; ++i) {
            pk0.v4[i] = (bf16)(o0[g * 4 + i] * inv);
            pk1.v4[i] = (bf16)(o1[g * 4 + i] * inv);
        }
        *(uint2*)(&orow[     g * 8 + hi * 4]) = pk0.u;
        *(uint2*)(&orow[32 + g * 8 + hi * 4]) = pk1.u;
    }
}

// ---------------- launch ----------------
extern "C" void kernel_launch(void* const* d_in, const int* in_sizes, int n_in,
                              void* d_out, int out_size, void* d_ws, size_t ws_size,
                              hipStream_t stream) {
    const float* x  = (const float*)d_in[0];
    // d_in[1] = mask (causal tril — analytic), d_in[7] = start_pos (==0)
    const float* Wq = (const float*)d_in[2];
    const float* Wk = (const float*)d_in[3];
    const float* Wv = (const float*)d_in[4];
    const float* Wo = (const float*)d_in[5];
    const float* bo = (const float*)d_in[6];
    float* out = (float*)d_out;

    char* p = (char*)d_ws;
    const size_t MK = 8192ull * 1024;
    bf16* xb  = (bf16*)p; p += MK * 2;
    bf16* wqb = (bf16*)p; p += (1ull << 20) * 2;
    bf16* wkb = (bf16*)p; p += (1ull << 20) * 2;
    bf16* wvb = (bf16*)p; p += (1ull << 20) * 2;
    bf16* wob = (bf16*)p; p += (1ull << 20) * 2;
    bf16* qb  = (bf16*)p; p += MK * 2;   // [B,H,T,64], scaled by 0.125*log2e
    bf16* kb  = (bf16*)p; p += MK * 2;   // [B,H,T,64]
    bf16* vtb = (bf16*)p; p += MK * 2;   // [B,H,64,T]
    bf16* aob = (bf16*)p; p += MK * 2;   // [B,T,1024]

    cvt_all<<<12288, 256, 0, stream>>>(x, Wq, Wk, Wv, Wo, xb, wqb, wkb, wvb, wob);

    gemm_qkv<<<1536, 256, 0, stream>>>(xb, wqb, wkb, wvb, qb, kb, vtb);
    flash_attn<<<1024, 256, 0, stream>>>(qb, kb, vtb, aob);
    gemm_out<<<512, 256, 0, stream>>>(aob, wob, bo, out);
}